// Round 1
// baseline (413.755 us; speedup 1.0000x reference)
//
#include <hip/hip_runtime.h>
#include <hip/hip_bf16.h>
#include <math.h>

#define N_NODES 50000
#define N_EDGES 1600000
#define N_FEAT  256
#define HIDDEN  32
#define N_CLASS 64
#define MLPB    782      // mlp blocks (64 nodes each)
#define HISTB   160      // histogram blocks (2500 int4 each = 10000 edges)
#define I4PB    2500     // int4 edge-quads per hist block (160*2500*4 = 1.6M)

typedef _Float16 half_t;
typedef _Float16 half8 __attribute__((ext_vector_type(8)));

__device__ __forceinline__ float half_tanh(float x) {
  // 0.5*tanh(x) = 0.5 - 1/(e^{2x}+1); exp->inf saturates correctly via rcp
  float e = __expf(2.f * x);
  return 0.5f - __builtin_amdgcn_rcpf(e + 1.f);
}

// ---------------- fused prep: blocks [0,MLPB) = MLP, [MLPB,MLPB+HISTB) = hist

__global__ __launch_bounds__(256) void prep_kernel(
    const float* __restrict__ x, const float* __restrict__ W1,
    const float* __restrict__ b1, const float* __restrict__ W2,
    const float* __restrict__ b2, half_t* __restrict__ P,
    const int* __restrict__ edst, int* __restrict__ deg) {
  __shared__ __align__(16) float fs[6528];   // 26,112 B -> 6 blocks/CU
  int t = threadIdx.x;

  if (blockIdx.x < MLPB) {
    // ---------- MLP + softmax -> fp16 P ----------
    float* xs = fs;                 // [256feat x 64node] rotate-swizzled (4096)
    float* ps = fs;                 // [64][65] (4160), aliases xs (dead)
    float* hfull = fs + 4416;       // [64][33]
    int w = __builtin_amdgcn_readfirstlane(t >> 6);   // 0..3
    int l = t & 63;
    int n0 = blockIdx.x * 64;
    int rowb = t >> 4, c4 = t & 15;
    int f0 = c4 * 4;

    float4 v[4];
#pragma unroll
    for (int p = 0; p < 4; ++p) {
      int row = rowb + 16 * p;
      v[p] = make_float4(0.f, 0.f, 0.f, 0.f);
      if (n0 + row < N_NODES)
        v[p] = *(const float4*)(x + (size_t)(n0 + row) * N_FEAT + f0);
    }

    float h[8];
#pragma unroll
    for (int j = 0; j < 8; ++j) h[j] = 0.f;

    for (int kc = 0; kc < 4; ++kc) {
#pragma unroll
      for (int p = 0; p < 4; ++p) {
        int row = rowb + 16 * p;
        int col = (row + f0) & 63;
        xs[(f0 + 0) * 64 + col] = v[p].x;
        xs[(f0 + 1) * 64 + col] = v[p].y;
        xs[(f0 + 2) * 64 + col] = v[p].z;
        xs[(f0 + 3) * 64 + col] = v[p].w;
      }
      __syncthreads();
      if (kc < 3) {
#pragma unroll
        for (int p = 0; p < 4; ++p) {
          int row = rowb + 16 * p;
          v[p] = make_float4(0.f, 0.f, 0.f, 0.f);
          if (n0 + row < N_NODES)
            v[p] = *(const float4*)(x + (size_t)(n0 + row) * N_FEAT + (kc + 1) * 64 + f0);
        }
      }
#pragma unroll 8
      for (int k = 0; k < 64; ++k) {
        float xk = xs[k * 64 + ((l + (k & 60)) & 63)];
        const float* wr = W1 + (size_t)(kc * 64 + k) * HIDDEN + 8 * w;  // uniform
#pragma unroll
        for (int j = 0; j < 8; ++j) h[j] = fmaf(xk, wr[j], h[j]);
      }
      __syncthreads();
    }

#pragma unroll
    for (int i = 0; i < 8; ++i)
      hfull[l * 33 + 8 * w + i] = fmaxf(h[i] + b1[8 * w + i], 0.f);
    __syncthreads();

    float pa[16];
#pragma unroll
    for (int c = 0; c < 16; ++c) pa[c] = b2[16 * w + c];
#pragma unroll 4
    for (int kk = 0; kk < 32; ++kk) {
      float hk = hfull[l * 33 + kk];
      const float* w2r = W2 + kk * N_CLASS + 16 * w;                    // uniform
#pragma unroll
      for (int c = 0; c < 16; ++c) pa[c] = fmaf(hk, w2r[c], pa[c]);
    }
#pragma unroll
    for (int c = 0; c < 16; ++c) ps[l * 65 + 16 * w + c] = pa[c];
    __syncthreads();

    {  // softmax: 4 threads per node
      int n = t >> 2, ck = (t & 3) * 16;
      float q[16];
      float m = -1e30f;
#pragma unroll
      for (int i = 0; i < 16; ++i) { q[i] = ps[n * 65 + ck + i]; m = fmaxf(m, q[i]); }
      m = fmaxf(m, __shfl_xor(m, 1));
      m = fmaxf(m, __shfl_xor(m, 2));
      float s = 0.f;
#pragma unroll
      for (int i = 0; i < 16; ++i) { q[i] = __expf(q[i] - m); s += q[i]; }
      s += __shfl_xor(s, 1);
      s += __shfl_xor(s, 2);
      float inv = 1.f / s;
      if (n0 + n < N_NODES) {
        half8 o0, o1;
#pragma unroll
        for (int i = 0; i < 8; ++i) {
          o0[i] = (half_t)(q[i] * inv);
          o1[i] = (half_t)(q[8 + i] * inv);
        }
        half_t* op = P + (size_t)(n0 + n) * N_CLASS + ck;
        *(half8*)op = o0;
        *(half8*)(op + 8) = o1;
      }
    }
  } else {
    // ---------- per-dst-node degree histogram ----------
    int hb = blockIdx.x - MLPB;
    int b0 = hb * I4PB;
    const int4* e4 = (const int4*)edst;
    for (int i = b0 + t; i < b0 + I4PB; i += 256) {
      int4 d4 = e4[i];
      atomicAdd(&deg[d4.x], 1);
      atomicAdd(&deg[d4.y], 1);
      atomicAdd(&deg[d4.z], 1);
      atomicAdd(&deg[d4.w], 1);
    }
  }
}

// ---------------- segment assignment: rr(beg,end) via wave-scan + 1 atomic ----

__global__ __launch_bounds__(256) void assign_kernel(const int* __restrict__ deg,
                                                     int* __restrict__ cur,
                                                     int2* __restrict__ rr,
                                                     int* __restrict__ gcur) {
  int n = blockIdx.x * 256 + threadIdx.x;
  int lane = threadIdx.x & 63;
  int d = (n < N_NODES) ? deg[n] : 0;
  int run = d;
#pragma unroll
  for (int off = 1; off < 64; off <<= 1) {
    int u = __shfl_up(run, off);
    if (lane >= off) run += u;
  }
  int tot = __shfl(run, 63);
  int base = 0;
  if (lane == 0 && tot > 0) base = atomicAdd(gcur, tot);
  base = __shfl(base, 0);
  int beg = base + run - d;
  if (n < N_NODES) {
    rr[n] = make_int2(beg, beg + d);
    cur[n] = beg;
  }
}

// ---------------- scatter edges into exact CSR ----------------

__global__ __launch_bounds__(256) void scatter_kernel(const int* __restrict__ esrc,
                                                      const int* __restrict__ edst,
                                                      const float* __restrict__ evl,
                                                      int* __restrict__ cur,
                                                      int2* __restrict__ ep) {
  int i = blockIdx.x * 256 + threadIdx.x;   // quad index in [0, 400000)
  if (i >= N_EDGES / 4) return;
  int4   s4 = ((const int4*)esrc)[i];
  int4   d4 = ((const int4*)edst)[i];
  float4 v4 = ((const float4*)evl)[i];
  int p0 = atomicAdd(&cur[d4.x], 1); ep[p0] = make_int2(s4.x, __float_as_int(v4.x));
  int p1 = atomicAdd(&cur[d4.y], 1); ep[p1] = make_int2(s4.y, __float_as_int(v4.y));
  int p2 = atomicAdd(&cur[d4.z], 1); ep[p2] = make_int2(s4.z, __float_as_int(v4.z));
  int p3 = atomicAdd(&cur[d4.w], 1); ep[p3] = make_int2(s4.w, __float_as_int(v4.w));
}

// ---------------- SpMM + 0.5*tanh (+ fused final softmax) ----------------
// R8-proven main loop: wave per dst node; one coalesced 64-edge block load per
// wave; shuffle broadcast; 8 edge-subgroups x 8 channel-octets, 16B gathers.
// Cheap epilogue: half_tanh / __expf.

template <int FINAL>
__global__ __launch_bounds__(256) void spmm_kernel(const int2* __restrict__ rr,
                                                   const long long* __restrict__ epl,
                                                   const half_t* __restrict__ pin,
                                                   void* __restrict__ pout_) {
  int node = blockIdx.x * 4 + (threadIdx.x >> 6);
  int lane = threadIdx.x & 63;
  int g = lane >> 3;     // edge subgroup 0..7
  int s = lane & 7;      // channel octet: channels 8s..8s+7
  int2 be = rr[node];
  int beg = be.x, end = be.y;
  float acc[8];
#pragma unroll
  for (int i = 0; i < 8; ++i) acc[i] = 0.f;
  for (int base = beg; base < end; base += 64) {
    int idx = base + lane;
    long long raw = (idx < end) ? __builtin_nontemporal_load(epl + idx) : 0LL;
    int ex = (int)raw;
    float ev = __int_as_float((int)(raw >> 32));
    int cnt = min(64, end - base);
#pragma unroll 4
    for (int j = g; j < cnt; j += 8) {
      int   sj = __shfl(ex, j);
      float vj = __shfl(ev, j);
      half8 hv = *(const half8*)(pin + ((size_t)sj << 6) + (s << 3));
#pragma unroll
      for (int i = 0; i < 8; ++i) acc[i] = fmaf(vj, (float)hv[i], acc[i]);
    }
  }
  // reduce across the 8 edge subgroups (lane bits 3,4,5)
#pragma unroll
  for (int off = 8; off <= 32; off <<= 1)
#pragma unroll
    for (int i = 0; i < 8; ++i) acc[i] += __shfl_xor(acc[i], off);
  float r[8];
#pragma unroll
  for (int i = 0; i < 8; ++i) r[i] = half_tanh(acc[i]);
  if (FINAL) {
    float m = r[0];
#pragma unroll
    for (int i = 1; i < 8; ++i) m = fmaxf(m, r[i]);
    m = fmaxf(m, __shfl_xor(m, 1));
    m = fmaxf(m, __shfl_xor(m, 2));
    m = fmaxf(m, __shfl_xor(m, 4));
    float e[8], sum = 0.f;
#pragma unroll
    for (int i = 0; i < 8; ++i) { e[i] = __expf(r[i] - m); sum += e[i]; }
    sum += __shfl_xor(sum, 1);
    sum += __shfl_xor(sum, 2);
    sum += __shfl_xor(sum, 4);
    float inv = 1.f / sum;
    if (g == 0) {
      float* op = (float*)pout_ + ((size_t)node << 6) + (s << 3);
      *(float4*)op = make_float4(e[0] * inv, e[1] * inv, e[2] * inv, e[3] * inv);
      *(float4*)(op + 4) = make_float4(e[4] * inv, e[5] * inv, e[6] * inv, e[7] * inv);
    }
  } else {
    if (g == 0) {
      half8 o;
#pragma unroll
      for (int i = 0; i < 8; ++i) o[i] = (half_t)r[i];
      *(half8*)((half_t*)pout_ + ((size_t)node << 6) + (s << 3)) = o;
    }
  }
}

// ---------------- launch ----------------

extern "C" void kernel_launch(void* const* d_in, const int* in_sizes, int n_in,
                              void* d_out, int out_size, void* d_ws, size_t ws_size,
                              hipStream_t stream) {
  const float* x    = (const float*)d_in[0];
  const int*   esrc = (const int*)d_in[1];
  const int*   edst = (const int*)d_in[2];
  const float* evl  = (const float*)d_in[3];
  const float* W1   = (const float*)d_in[4];
  const float* b1   = (const float*)d_in[5];
  const float* W2   = (const float*)d_in[6];
  const float* b2   = (const float*)d_in[7];

  char* ws = (char*)d_ws;
  int2*   ep   = (int2*)  (ws);               // 12,800,000 B (exact CSR)
  half_t* Pa   = (half_t*)(ws + 12800000);    // 6.4 MB
  half_t* Pb   = (half_t*)(ws + 19200000);    // 6.4 MB
  int*    deg  = (int*)   (ws + 25600000);    // 200,000 B
  int*    gcur = (int*)   (ws + 25800000);    // 4 B (padded to 64)
  int*    cur  = (int*)   (ws + 25800064);    // 200,000 B
  int2*   rr   = (int2*)  (ws + 26000064);    // 400,000 B -> ends 26,400,064

  // zero deg + gcur in one shot
  hipMemsetAsync(ws + 25600000, 0, 200064, stream);

  prep_kernel<<<MLPB + HISTB, 256, 0, stream>>>(x, W1, b1, W2, b2, Pa, edst, deg);
  assign_kernel<<<196, 256, 0, stream>>>(deg, cur, rr, gcur);
  scatter_kernel<<<1563, 256, 0, stream>>>(esrc, edst, evl, cur, ep);

  const long long* epl = (const long long*)ep;
  spmm_kernel<0><<<12500, 256, 0, stream>>>(rr, epl, Pa, (void*)Pb);
  spmm_kernel<0><<<12500, 256, 0, stream>>>(rr, epl, Pb, (void*)Pa);
  spmm_kernel<0><<<12500, 256, 0, stream>>>(rr, epl, Pa, (void*)Pb);
  spmm_kernel<1><<<12500, 256, 0, stream>>>(rr, epl, Pb, d_out);
}